// Round 1
// baseline (683.249 us; speedup 1.0000x reference)
//
#include <hip/hip_runtime.h>
#include <hip/hip_bf16.h>

// Problem constants (fixed by setup_inputs)
#define BB  8
#define CC  256
#define HW  4096      // 64*64
#define CQ  32
#define CV  128
#define MP  1024      // pooled positions (32*32)

// Workspace layout (floats). Total 11,796,480 floats = 47.2 MB.
#define Y_OFF   0                      // y   [B][192][HW]  rows 0-31 q, 32-63 k, 64-191 v
#define KP_OFF  (BB*192*HW)            // kp  [B][32][MP]
#define VT_OFF  (KP_OFF + BB*CQ*MP)    // vT  [B][MP][CV]
#define CT_OFF  (VT_OFF + BB*MP*CV)    // ctx [B][HW][CV]

// ---------------------------------------------------------------------------
// Kernel 1: fused q/k/v 1x1 conv at full resolution -> y[b][o][p], o in [0,192)
// block: 256 thr; tile = 256 positions x 48 outputs; weights staged in LDS.
// ---------------------------------------------------------------------------
__global__ __launch_bounds__(256) void k_qkv(
    const float* __restrict__ x, const float* __restrict__ wq,
    const float* __restrict__ wk, const float* __restrict__ wv,
    float* __restrict__ y)
{
    __shared__ float w_lds[48 * 256];
    const int bid = blockIdx.x;
    const int oc = bid & 3;            // output chunk (48 rows)
    const int pt = (bid >> 2) & 15;    // position tile (256 positions)
    const int b  = bid >> 6;
    const int o0 = oc * 48;
    const int p0 = pt * 256;
    const int tid = threadIdx.x;

    for (int idx = tid; idx < 48 * 256; idx += 256) {
        int o = o0 + (idx >> 8);
        int c = idx & 255;
        float w;
        if (o < 32)      w = wq[o * 256 + c];
        else if (o < 64) w = wk[(o - 32) * 256 + c];
        else             w = wv[(o - 64) * 256 + c];
        w_lds[idx] = w;
    }
    __syncthreads();

    const int lane = tid & 63;
    const int og   = __builtin_amdgcn_readfirstlane(tid >> 6);  // wave-uniform
    float acc[4][12];
    #pragma unroll
    for (int k = 0; k < 4; ++k)
        #pragma unroll
        for (int j = 0; j < 12; ++j) acc[k][j] = 0.f;

    const float* xp = x + (long)(b * CC) * HW + p0 + lane;
    const float* wl = &w_lds[og * 12 * 256];

    for (int c4 = 0; c4 < 64; ++c4) {
        float xv[4][4];                 // [cc][k]
        #pragma unroll
        for (int cc = 0; cc < 4; ++cc) {
            xv[cc][0] = xp[0]; xv[cc][1] = xp[64];
            xv[cc][2] = xp[128]; xv[cc][3] = xp[192];
            xp += HW;
        }
        #pragma unroll
        for (int j = 0; j < 12; ++j) {
            const float4 w = *(const float4*)&wl[j * 256 + c4 * 4];
            #pragma unroll
            for (int k = 0; k < 4; ++k)
                acc[k][j] += w.x * xv[0][k] + w.y * xv[1][k]
                           + w.z * xv[2][k] + w.w * xv[3][k];
        }
    }

    float* yp = y + (long)(b * 192 + o0 + og * 12) * HW + p0 + lane;
    #pragma unroll
    for (int j = 0; j < 12; ++j)
        #pragma unroll
        for (int k = 0; k < 4; ++k)
            yp[(long)j * HW + 64 * k] = acc[k][j];
}

// ---------------------------------------------------------------------------
// Kernel 2: 2x2 maxpool. k channels direct (channel-major), v transposed via
// LDS to vT[b][m][c] so the attention PV step reads coalesced rows.
// ---------------------------------------------------------------------------
__global__ __launch_bounds__(256) void k_pool(
    const float* __restrict__ y, float* __restrict__ kp, float* __restrict__ vT)
{
    __shared__ float t[128 * 65];
    const int bid = blockIdx.x;
    const int ppt = bid & 15;          // 64 pooled positions (2 pooled rows)
    const int b   = bid >> 4;
    const int pp0 = ppt * 64;
    const int tid = threadIdx.x;

    for (int idx = tid; idx < 32 * 64; idx += 256) {
        int o = idx >> 6, ppl = idx & 63;
        int pp = pp0 + ppl;
        int ph = pp >> 5, pw = pp & 31;
        const float* s = y + (long)(b * 192 + 32 + o) * HW + (ph * 2) * 64 + pw * 2;
        kp[(b * CQ + o) * MP + pp] = fmaxf(fmaxf(s[0], s[1]), fmaxf(s[64], s[65]));
    }
    for (int idx = tid; idx < 128 * 64; idx += 256) {
        int c = idx >> 6, ppl = idx & 63;
        int pp = pp0 + ppl;
        int ph = pp >> 5, pw = pp & 31;
        const float* s = y + (long)(b * 192 + 64 + c) * HW + (ph * 2) * 64 + pw * 2;
        t[c * 65 + ppl] = fmaxf(fmaxf(s[0], s[1]), fmaxf(s[64], s[65]));
    }
    __syncthreads();
    for (int idx = tid; idx < 64 * 128; idx += 256) {
        int ppl = idx >> 7, c = idx & 127;
        vT[(long)(b * MP + pp0 + ppl) * CV + c] = t[c * 65 + ppl];
    }
}

// ---------------------------------------------------------------------------
// Kernel 3: flash-style attention. Block = 64 queries (4 waves x 16 q/wave),
// loop m-tiles of 64 staging k[32][64] + vT[64][128] in LDS, online softmax.
// Lane owns m (scores phase) then c & c+64 (PV phase); transpose via a_lds.
// LDS = 9.2 + 8 + 32 + 16 KB = 65.5 KB -> 2 blocks/CU.
// ---------------------------------------------------------------------------
__global__ __launch_bounds__(256) void k_attn(
    const float* __restrict__ y, const float* __restrict__ kp,
    const float* __restrict__ vT, float* __restrict__ ctxT)
{
    __shared__ float q_lds[64 * 36];   // pad 36: fp32x4-aligned, conflict-free
    __shared__ float k_lds[32 * 64];
    __shared__ float v_lds[64 * 128];
    __shared__ float a_lds[64 * 64];
    const int bid = blockIdx.x;
    const int nt = bid & 63;
    const int b  = bid >> 6;
    const int n0 = nt * 64;
    const int tid  = threadIdx.x;
    const int lane = tid & 63;
    const int wid  = tid >> 6;
    const int w16  = wid * 16;

    for (int idx = tid; idx < 64 * 32; idx += 256) {
        int o = idx >> 6, nl = idx & 63;
        q_lds[nl * 36 + o] = y[(long)(b * 192 + o) * HW + n0 + nl];
    }

    float m_run[16], l_run[16], acc0[16], acc1[16];
    #pragma unroll
    for (int qi = 0; qi < 16; ++qi) {
        m_run[qi] = -INFINITY; l_run[qi] = 0.f; acc0[qi] = 0.f; acc1[qi] = 0.f;
    }

    for (int mt = 0; mt < 16; ++mt) {
        __syncthreads();               // prior-tile consumers done (also fences q stage)
        const int m0 = mt * 64;
        for (int idx = tid; idx < 32 * 64; idx += 256) {
            int o = idx >> 6, ml = idx & 63;
            k_lds[idx] = kp[(b * CQ + o) * MP + m0 + ml];
        }
        for (int idx = tid; idx < 64 * 128; idx += 256) {
            int ml = idx >> 7, c = idx & 127;
            v_lds[idx] = vT[(long)(b * MP + m0 + ml) * CV + c];
        }
        __syncthreads();

        // scores: s[qi] for m = lane
        float s[16];
        #pragma unroll
        for (int qi = 0; qi < 16; ++qi) s[qi] = 0.f;
        #pragma unroll
        for (int og = 0; og < 8; ++og) {
            float k0 = k_lds[(og * 4 + 0) * 64 + lane];
            float k1 = k_lds[(og * 4 + 1) * 64 + lane];
            float k2 = k_lds[(og * 4 + 2) * 64 + lane];
            float k3 = k_lds[(og * 4 + 3) * 64 + lane];
            #pragma unroll
            for (int qi = 0; qi < 16; ++qi) {
                const float4 qv = *(const float4*)&q_lds[(w16 + qi) * 36 + og * 4];
                s[qi] += qv.x * k0 + qv.y * k1 + qv.z * k2 + qv.w * k3;
            }
        }

        // online softmax per query (reduce across 64 lanes = 64 m's)
        #pragma unroll
        for (int qi = 0; qi < 16; ++qi) {
            float tm = s[qi];
            #pragma unroll
            for (int off = 32; off > 0; off >>= 1)
                tm = fmaxf(tm, __shfl_xor(tm, off, 64));
            float nm    = fmaxf(m_run[qi], tm);
            float alpha = __expf(m_run[qi] - nm);   // 0 when m_run = -inf
            float p     = __expf(s[qi] - nm);
            float ts = p;
            #pragma unroll
            for (int off = 32; off > 0; off >>= 1)
                ts += __shfl_xor(ts, off, 64);
            l_run[qi] = l_run[qi] * alpha + ts;
            m_run[qi] = nm;
            a_lds[(w16 + qi) * 64 + lane] = p;      // own-wave rows only
            acc0[qi] *= alpha; acc1[qi] *= alpha;
        }

        // PV: lane owns c=lane and c=lane+64
        #pragma unroll
        for (int mp = 0; mp < 32; ++mp) {
            const int m = mp * 2;
            float v00 = v_lds[m * 128 + lane];
            float v01 = v_lds[m * 128 + 64 + lane];
            float v10 = v_lds[(m + 1) * 128 + lane];
            float v11 = v_lds[(m + 1) * 128 + 64 + lane];
            #pragma unroll
            for (int qi = 0; qi < 16; ++qi) {
                const float2 a = *(const float2*)&a_lds[(w16 + qi) * 64 + m];
                acc0[qi] += a.x * v00 + a.y * v10;
                acc1[qi] += a.x * v01 + a.y * v11;
            }
        }
    }

    #pragma unroll
    for (int qi = 0; qi < 16; ++qi) {
        float inv = 1.f / l_run[qi];
        int n = n0 + w16 + qi;
        ctxT[(long)(b * HW + n) * CV + lane]      = acc0[qi] * inv;
        ctxT[(long)(b * HW + n) * CV + 64 + lane] = acc1[qi] * inv;
    }
}

// ---------------------------------------------------------------------------
// Kernel 4: out = gamma * wo @ ctx + x. ctx tile staged in LDS (pad 129),
// wo rows via wave-uniform (scalar) loads; 4 outputs per thread per group.
// ---------------------------------------------------------------------------
__global__ __launch_bounds__(256) void k_out(
    const float* __restrict__ ctxT, const float* __restrict__ wo,
    const float* __restrict__ x, const float* __restrict__ gamma,
    float* __restrict__ out)
{
    __shared__ float t[64 * 129];
    const int bid = blockIdx.x;
    const int pt = bid & 63;
    const int b  = bid >> 6;
    const int p0 = pt * 64;
    const int tid = threadIdx.x;

    for (int idx = tid; idx < 64 * 128; idx += 256) {
        int pl = idx >> 7, c = idx & 127;
        t[pl * 129 + c] = ctxT[(long)(b * HW + p0 + pl) * CV + c];
    }
    __syncthreads();

    const int lane = tid & 63;
    const int wid  = __builtin_amdgcn_readfirstlane(tid >> 6);
    const float gma = gamma[0];
    const float* tl = &t[lane * 129];

    for (int g = 0; g < 16; ++g) {
        const int co = wid * 64 + g * 4;
        const float* w0 = wo + co * 128;
        const float* w1 = w0 + 128;
        const float* w2 = w1 + 128;
        const float* w3 = w2 + 128;
        float a0 = 0.f, a1 = 0.f, a2 = 0.f, a3 = 0.f;
        #pragma unroll 8
        for (int c = 0; c < 128; ++c) {
            float v = tl[c];
            a0 += w0[c] * v; a1 += w1[c] * v; a2 += w2[c] * v; a3 += w3[c] * v;
        }
        const int p = p0 + lane;
        const long base = (long)(b * CC + co) * HW + p;
        out[base]            = gma * a0 + x[base];
        out[base + HW]       = gma * a1 + x[base + HW];
        out[base + 2L * HW]  = gma * a2 + x[base + 2L * HW];
        out[base + 3L * HW]  = gma * a3 + x[base + 3L * HW];
    }
}

// ---------------------------------------------------------------------------
extern "C" void kernel_launch(void* const* d_in, const int* in_sizes, int n_in,
                              void* d_out, int out_size, void* d_ws, size_t ws_size,
                              hipStream_t stream) {
    const float* x     = (const float*)d_in[0];
    const float* wq    = (const float*)d_in[1];
    const float* wk    = (const float*)d_in[2];
    const float* wv    = (const float*)d_in[3];
    const float* wo    = (const float*)d_in[4];
    const float* gamma = (const float*)d_in[5];
    float* out = (float*)d_out;
    float* ws  = (float*)d_ws;   // needs 47.2 MB

    float* y   = ws + Y_OFF;
    float* kp  = ws + KP_OFF;
    float* vT  = ws + VT_OFF;
    float* ctx = ws + CT_OFF;

    k_qkv <<<dim3(512), dim3(256), 0, stream>>>(x, wq, wk, wv, y);
    k_pool<<<dim3(128), dim3(256), 0, stream>>>(y, kp, vT);
    k_attn<<<dim3(512), dim3(256), 0, stream>>>(y, kp, vT, ctx);
    k_out <<<dim3(512), dim3(256), 0, stream>>>(ctx, wo, x, gamma, out);
}

// Round 2
// 161.633 us; speedup vs baseline: 4.2272x; 4.2272x over previous
//
#include <hip/hip_runtime.h>
#include <hip/hip_bf16.h>

// Problem constants
#define BB  8
#define CC  256
#define HW  4096      // 64*64
#define CQ  32
#define CV  128
#define MP  1024      // pooled positions (32*32)

// Workspace layout (float offsets)
#define Y_OFF   0                          // y   [B][192][HW] fp32 (q rows 0-31, k 32-63, v 64-191)
#define KT_OFF  (BB*192*HW)                // kT  [B][MP][32]  bf16
#define VP_OFF  (KT_OFF + BB*MP*CQ/2)      // vp  [B][CV][MP]  bf16
#define CT_OFF  (VP_OFF + BB*CV*MP/2)      // ctx [B][CV][HW]  fp32

typedef __attribute__((ext_vector_type(8))) short bf16x8;
typedef __attribute__((ext_vector_type(4))) short bf16x4;
typedef __attribute__((ext_vector_type(4))) float f32x4;

__device__ __forceinline__ short f2b(float f) {   // fp32 -> bf16 bits, RNE
    unsigned u = __float_as_uint(f);
    u += 0x7fffu + ((u >> 16) & 1u);
    return (short)(u >> 16);
}

// ---------------------------------------------------------------------------
// Kernel 1: fused q/k/v 1x1 conv -> y[b][o][p] fp32, o in [0,192)
// ---------------------------------------------------------------------------
__global__ __launch_bounds__(256) void k_qkv(
    const float* __restrict__ x, const float* __restrict__ wq,
    const float* __restrict__ wk, const float* __restrict__ wv,
    float* __restrict__ y)
{
    __shared__ float w_lds[48 * 256];
    const int bid = blockIdx.x;
    const int oc = bid & 3;
    const int pt = (bid >> 2) & 15;
    const int b  = bid >> 6;
    const int o0 = oc * 48;
    const int p0 = pt * 256;
    const int tid = threadIdx.x;

    for (int idx = tid; idx < 48 * 256; idx += 256) {
        int o = o0 + (idx >> 8);
        int c = idx & 255;
        float w;
        if (o < 32)      w = wq[o * 256 + c];
        else if (o < 64) w = wk[(o - 32) * 256 + c];
        else             w = wv[(o - 64) * 256 + c];
        w_lds[idx] = w;
    }
    __syncthreads();

    const int lane = tid & 63;
    const int og   = __builtin_amdgcn_readfirstlane(tid >> 6);
    float acc[4][12];
    #pragma unroll
    for (int k = 0; k < 4; ++k)
        #pragma unroll
        for (int j = 0; j < 12; ++j) acc[k][j] = 0.f;

    const float* xp = x + (long)(b * CC) * HW + p0 + lane;
    const float* wl = &w_lds[og * 12 * 256];

    for (int c4 = 0; c4 < 64; ++c4) {
        float xv[4][4];
        #pragma unroll
        for (int cc = 0; cc < 4; ++cc) {
            xv[cc][0] = xp[0]; xv[cc][1] = xp[64];
            xv[cc][2] = xp[128]; xv[cc][3] = xp[192];
            xp += HW;
        }
        #pragma unroll
        for (int j = 0; j < 12; ++j) {
            const float4 w = *(const float4*)&wl[j * 256 + c4 * 4];
            #pragma unroll
            for (int k = 0; k < 4; ++k)
                acc[k][j] += w.x * xv[0][k] + w.y * xv[1][k]
                           + w.z * xv[2][k] + w.w * xv[3][k];
        }
    }

    float* yp = y + (long)(b * 192 + o0 + og * 12) * HW + p0 + lane;
    #pragma unroll
    for (int j = 0; j < 12; ++j)
        #pragma unroll
        for (int k = 0; k < 4; ++k)
            yp[(long)j * HW + 64 * k] = acc[k][j];
}

// ---------------------------------------------------------------------------
// Kernel 2: 2x2 maxpool. k -> kT[b][m][32] bf16 (transposed via LDS),
// v -> vp[b][c][m] bf16 (channel-major, direct, coalesced).
// ---------------------------------------------------------------------------
__global__ __launch_bounds__(256) void k_pool(
    const float* __restrict__ y, short* __restrict__ kT, short* __restrict__ vp)
{
    __shared__ float t[32 * 65];
    const int bid = blockIdx.x;
    const int ppt = bid & 15;
    const int b   = bid >> 4;
    const int pp0 = ppt * 64;
    const int tid = threadIdx.x;

    for (int idx = tid; idx < 32 * 64; idx += 256) {
        int o = idx >> 6, ppl = idx & 63;
        int pp = pp0 + ppl;
        int ph = pp >> 5, pw = pp & 31;
        const float* s = y + (long)(b * 192 + 32 + o) * HW + ph * 128 + pw * 2;
        t[o * 65 + ppl] = fmaxf(fmaxf(s[0], s[1]), fmaxf(s[64], s[65]));
    }
    for (int idx = tid; idx < 128 * 64; idx += 256) {
        int c = idx >> 6, ppl = idx & 63;
        int pp = pp0 + ppl;
        int ph = pp >> 5, pw = pp & 31;
        const float* s = y + (long)(b * 192 + 64 + c) * HW + ph * 128 + pw * 2;
        vp[(b * CV + c) * MP + pp] = f2b(fmaxf(fmaxf(s[0], s[1]), fmaxf(s[64], s[65])));
    }
    __syncthreads();
    for (int idx = tid; idx < 64 * 32; idx += 256) {
        int ppl = idx >> 5, c = idx & 31;
        kT[(b * MP + pp0 + ppl) * CQ + c] = f2b(t[c * 65 + ppl]);
    }
}

// ---------------------------------------------------------------------------
// Kernel 3: MFMA flash attention. Block = 128 thr (2 waves), wave = 32 queries
// (2 subtiles of 16). Swapped QK^T: S^T = mfma(A=kT tile, B=Q^T frag) so each
// lane holds 8 P-values of one q-row -> in-lane softmax + 2 shfl_xor.
// PV: ctx^T = mfma(A=V channel-major tile, B=P^T from small LDS relayout).
// K/V frags load straight from global (L2-resident: 320 KB/batch).
// ---------------------------------------------------------------------------
__global__ __launch_bounds__(128) void k_attn(
    const float* __restrict__ y,      // q rows: y[b][0..31][HW]
    const short* __restrict__ kT,     // [b][1024][32] bf16
    const short* __restrict__ vp,     // [b][128][1024] bf16
    float* __restrict__ ctx)          // [b][128][4096] fp32
{
    __shared__ short p_lds[2][2][16][40];   // [wave][subtile][q][m-local], pad 40
    const int tid  = threadIdx.x;
    const int lane = tid & 63;
    const int wid  = tid >> 6;
    const int b    = blockIdx.x >> 6;
    const int q0   = (blockIdx.x & 63) * 64 + wid * 32;
    const int l15  = lane & 15;
    const int g    = lane >> 4;

    // Q B-frags: B[c][q], col=q=l15, k=c=8g+i. Gather from channel-major fp32.
    bf16x8 qf[2];
    const float* yq = y + (long)b * 192 * HW;
    #pragma unroll
    for (int si = 0; si < 2; ++si)
        #pragma unroll
        for (int i = 0; i < 8; ++i)
            qf[si][i] = f2b(yq[(8 * g + i) * HW + q0 + si * 16 + l15]);

    float m_run[2] = {-INFINITY, -INFINITY};
    float l_run[2] = {0.f, 0.f};
    f32x4 acc[2][8];
    #pragma unroll
    for (int si = 0; si < 2; ++si)
        #pragma unroll
        for (int ct = 0; ct < 8; ++ct)
            acc[si][ct] = (f32x4){0.f, 0.f, 0.f, 0.f};

    const short* kTb = kT + (long)b * MP * CQ;
    const short* vpb = vp + (long)b * CV * MP;

    for (int mt = 0; mt < 32; ++mt) {
        const int m0 = mt * 32;
        // K A-frags: A[m][c], row=m-local=l15, k=c=8g+i
        bf16x8 ka0 = *(const bf16x8*)&kTb[(m0 + l15) * CQ + 8 * g];
        bf16x8 ka1 = *(const bf16x8*)&kTb[(m0 + 16 + l15) * CQ + 8 * g];
        // V A-frags: A[c][m], row=c-local=l15, k=m=8g+i
        bf16x8 va[8];
        #pragma unroll
        for (int ct = 0; ct < 8; ++ct)
            va[ct] = *(const bf16x8*)&vpb[(ct * 16 + l15) * MP + m0 + 8 * g];

        #pragma unroll
        for (int si = 0; si < 2; ++si) {
            f32x4 s0 = (f32x4){0.f, 0.f, 0.f, 0.f};
            f32x4 s1 = (f32x4){0.f, 0.f, 0.f, 0.f};
            s0 = __builtin_amdgcn_mfma_f32_16x16x32_bf16(ka0, qf[si], s0, 0, 0, 0);
            s1 = __builtin_amdgcn_mfma_f32_16x16x32_bf16(ka1, qf[si], s1, 0, 0, 0);
            // lane holds S[q=l15][m0 + {4g+r, 16+4g+r}]
            float tmax = fmaxf(fmaxf(fmaxf(s0[0], s0[1]), fmaxf(s0[2], s0[3])),
                               fmaxf(fmaxf(s1[0], s1[1]), fmaxf(s1[2], s1[3])));
            tmax = fmaxf(tmax, __shfl_xor(tmax, 16, 64));
            tmax = fmaxf(tmax, __shfl_xor(tmax, 32, 64));
            float mr = m_run[si];
            if (!__all(tmax <= mr + 8.0f)) {      // defer-rescale (T13)
                float nm = fmaxf(mr, tmax);
                float alpha = __expf(mr - nm);    // 0 on first tile
                l_run[si] *= alpha;
                #pragma unroll
                for (int ct = 0; ct < 8; ++ct) {
                    acc[si][ct][0] *= alpha; acc[si][ct][1] *= alpha;
                    acc[si][ct][2] *= alpha; acc[si][ct][3] *= alpha;
                }
                m_run[si] = nm;
                mr = nm;
            }
            float p[8];
            #pragma unroll
            for (int r = 0; r < 4; ++r) { p[r] = __expf(s0[r] - mr); p[4 + r] = __expf(s1[r] - mr); }
            float ts = ((p[0] + p[1]) + (p[2] + p[3])) + ((p[4] + p[5]) + (p[6] + p[7]));
            ts += __shfl_xor(ts, 16, 64);
            ts += __shfl_xor(ts, 32, 64);
            l_run[si] += ts;
            bf16x4 w0 = { f2b(p[0]), f2b(p[1]), f2b(p[2]), f2b(p[3]) };
            bf16x4 w1 = { f2b(p[4]), f2b(p[5]), f2b(p[6]), f2b(p[7]) };
            *(bf16x4*)&p_lds[wid][si][l15][4 * g]      = w0;   // m-local 4g+r
            *(bf16x4*)&p_lds[wid][si][l15][16 + 4 * g] = w1;   // m-local 16+4g+r
        }
        // PV: B[m][q] = P^T, col=q=l15, k=m=8g+i
        #pragma unroll
        for (int si = 0; si < 2; ++si) {
            bf16x8 pf = *(const bf16x8*)&p_lds[wid][si][l15][8 * g];
            #pragma unroll
            for (int ct = 0; ct < 8; ++ct)
                acc[si][ct] = __builtin_amdgcn_mfma_f32_16x16x32_bf16(va[ct], pf, acc[si][ct], 0, 0, 0);
        }
    }

    #pragma unroll
    for (int si = 0; si < 2; ++si) {
        float inv = 1.f / l_run[si];
        float* cb = ctx + (long)b * CV * HW + q0 + si * 16 + l15;
        #pragma unroll
        for (int ct = 0; ct < 8; ++ct)
            #pragma unroll
            for (int r = 0; r < 4; ++r)
                cb[(long)(ct * 16 + 4 * g + r) * HW] = acc[si][ct][r] * inv;
    }
}

// ---------------------------------------------------------------------------
// Kernel 4: out = gamma * wo @ ctx + x, ctx channel-major [b][128][4096].
// Same structure as k_qkv (broadcast LDS weights, coalesced position loads).
// ---------------------------------------------------------------------------
__global__ __launch_bounds__(256) void k_out(
    const float* __restrict__ ctx, const float* __restrict__ wo,
    const float* __restrict__ x, const float* __restrict__ gamma,
    float* __restrict__ out)
{
    __shared__ float w_lds[64 * 128];
    const int bid = blockIdx.x;
    const int oc = bid & 3;
    const int pt = (bid >> 2) & 15;
    const int b  = bid >> 6;
    const int o0 = oc * 64;
    const int p0 = pt * 256;
    const int tid = threadIdx.x;

    for (int idx = tid; idx < 64 * 128; idx += 256)
        w_lds[idx] = wo[(o0 + (idx >> 7)) * CV + (idx & 127)];
    __syncthreads();

    const int lane = tid & 63;
    const int og   = __builtin_amdgcn_readfirstlane(tid >> 6);
    float acc[4][16];
    #pragma unroll
    for (int k = 0; k < 4; ++k)
        #pragma unroll
        for (int j = 0; j < 16; ++j) acc[k][j] = 0.f;

    const float* cp = ctx + (long)b * CV * HW + p0 + lane;
    const float* wl = &w_lds[og * 16 * 128];

    for (int c4 = 0; c4 < 32; ++c4) {
        float xv[4][4];
        #pragma unroll
        for (int cc = 0; cc < 4; ++cc) {
            xv[cc][0] = cp[0]; xv[cc][1] = cp[64];
            xv[cc][2] = cp[128]; xv[cc][3] = cp[192];
            cp += HW;
        }
        #pragma unroll
        for (int j = 0; j < 16; ++j) {
            const float4 w = *(const float4*)&wl[j * 128 + c4 * 4];
            #pragma unroll
            for (int k = 0; k < 4; ++k)
                acc[k][j] += w.x * xv[0][k] + w.y * xv[1][k]
                           + w.z * xv[2][k] + w.w * xv[3][k];
        }
    }

    const float gma = gamma[0];
    const long obase = (long)(b * CC + o0 + og * 16) * HW + p0 + lane;
    #pragma unroll
    for (int j = 0; j < 16; ++j)
        #pragma unroll
        for (int k = 0; k < 4; ++k)
            out[obase + (long)j * HW + 64 * k] =
                gma * acc[k][j] + x[obase + (long)j * HW + 64 * k];
}

// ---------------------------------------------------------------------------
extern "C" void kernel_launch(void* const* d_in, const int* in_sizes, int n_in,
                              void* d_out, int out_size, void* d_ws, size_t ws_size,
                              hipStream_t stream) {
    const float* x     = (const float*)d_in[0];
    const float* wq    = (const float*)d_in[1];
    const float* wk    = (const float*)d_in[2];
    const float* wv    = (const float*)d_in[3];
    const float* wo    = (const float*)d_in[4];
    const float* gamma = (const float*)d_in[5];
    float* out = (float*)d_out;
    float* ws  = (float*)d_ws;

    float* y   = ws + Y_OFF;
    short* kT  = (short*)(ws + KT_OFF);
    short* vp  = (short*)(ws + VP_OFF);
    float* ctx = ws + CT_OFF;

    k_qkv <<<dim3(512), dim3(256), 0, stream>>>(x, wq, wk, wv, y);
    k_pool<<<dim3(128), dim3(256), 0, stream>>>(y, kT, vp);
    k_attn<<<dim3(512), dim3(128), 0, stream>>>(y, kT, vp, ctx);
    k_out <<<dim3(512), dim3(256), 0, stream>>>(ctx, wo, x, gamma, out);
}

// Round 3
// 98.322 us; speedup vs baseline: 6.9491x; 1.6439x over previous
//
#include <hip/hip_runtime.h>
#include <hip/hip_bf16.h>

// Problem constants
#define BB  8
#define CC  256
#define HW  4096      // 64*64
#define CQ  32
#define CV  128
#define MP  1024      // pooled positions (32*32)

// Workspace layout (float offsets). Total 10,092,544 floats = 40.4 MB.
#define XT_OFF  0                      // xt  [B][HW][256] bf16 (position-major x)
#define Y_OFF   4194304                // y   [B][HW][192] bf16 position-major (q 0-31, k 32-63, v 64-191)
#define KT_OFF  (Y_OFF + 3145728)      // kT  [B][MP][32]  bf16
#define VP_OFF  (KT_OFF + 131072)      // vp  [B][CV][MP]  bf16
#define CT_OFF  (VP_OFF + 524288)      // ctx [B][HW][CV]  bf16 position-major

typedef __attribute__((ext_vector_type(8))) short bf16x8;
typedef __attribute__((ext_vector_type(4))) short short4v;
typedef __attribute__((ext_vector_type(4))) float f32x4;

__device__ __forceinline__ short f2b(float f) {   // fp32 -> bf16 bits, RNE
    unsigned u = __float_as_uint(f);
    u += 0x7fffu + ((u >> 16) & 1u);
    return (short)(u >> 16);
}
__device__ __forceinline__ float b2f(short s) {
    return __uint_as_float(((unsigned)(unsigned short)s) << 16);
}

// ---------------------------------------------------------------------------
// Kernel 0: transpose+convert x[b][c][n] fp32 -> xt[b][n][c] bf16.
// 64x64 tiles via LDS (pad 65), both sides coalesced, conflict-free.
// ---------------------------------------------------------------------------
__global__ __launch_bounds__(256) void k_xt(
    const float* __restrict__ x, short* __restrict__ xt)
{
    __shared__ float t[64][65];
    const int bid = blockIdx.x;
    const int nt = bid & 63;
    const int ct = (bid >> 6) & 3;
    const int b  = bid >> 8;
    const int c0 = ct * 64, n0 = nt * 64;
    const int tid = threadIdx.x;

    const int col = tid & 63, wrow = (tid >> 6) * 16;
    #pragma unroll
    for (int i = 0; i < 16; ++i) {
        int r = wrow + i;
        t[r][col] = x[((long)(b * CC + c0 + r)) * HW + n0 + col];
    }
    __syncthreads();

    const int n = tid >> 2, cb = (tid & 3) * 16;
    short buf[16];
    #pragma unroll
    for (int j = 0; j < 16; ++j) buf[j] = f2b(t[cb + j][n]);
    short* dst = &xt[((long)(b * HW + n0 + n)) * CC + c0 + cb];
    *(int4*)dst = *(int4*)&buf[0];
    *(int4*)(dst + 8) = *(int4*)&buf[8];
}

// ---------------------------------------------------------------------------
// Kernel 1: qkv conv as bf16 MFMA GEMM. D[row=n][col=o], A = xt rows (LDS),
// B = W^T (= natural W rows, LDS). Output y_pm[b][n][192] bf16.
// Block: 256 thr (4 waves), tile n=256 x o=96, K=256 in 8 steps.
// LDS: W 96x264 (50.7KB) + x 256x40 (20.5KB) = 71 KB -> 2 blocks/CU.
// ---------------------------------------------------------------------------
__global__ __launch_bounds__(256) void k_qkv(
    const float* __restrict__ wq, const float* __restrict__ wk,
    const float* __restrict__ wv, const short* __restrict__ xt,
    short* __restrict__ y)
{
    __shared__ short w_lds[96 * 264];
    __shared__ short x_lds[256 * 40];
    const int bid = blockIdx.x;
    const int oc = bid & 1;
    const int nt = (bid >> 1) & 15;
    const int b  = bid >> 5;
    const int o0 = oc * 96, n0 = nt * 256;
    const int tid = threadIdx.x;
    const int lane = tid & 63;
    const int wvid = tid >> 6;
    const int l15 = lane & 15, g = lane >> 4;

    // stage W (f32 -> bf16), rows o0..o0+95
    for (int it = 0; it < 24; ++it) {
        int idx = tid + it * 256;            // quad index over 96*64
        int ol = idx >> 6, cq = (idx & 63) * 4;
        int o = o0 + ol;
        const float* src = (o < 32) ? &wq[o * 256 + cq]
                         : (o < 64) ? &wk[(o - 32) * 256 + cq]
                                    : &wv[(o - 64) * 256 + cq];
        float4 w = *(const float4*)src;
        short4v p = { f2b(w.x), f2b(w.y), f2b(w.z), f2b(w.w) };
        *(short4v*)&w_lds[ol * 264 + cq] = p;
    }

    f32x4 acc[4][6];
    #pragma unroll
    for (int nf = 0; nf < 4; ++nf)
        #pragma unroll
        for (int of = 0; of < 6; ++of) acc[nf][of] = (f32x4){0.f, 0.f, 0.f, 0.f};

    for (int ks = 0; ks < 8; ++ks) {
        __syncthreads();
        // stage xt slice [256 n][32 k] -> x_lds[n][40]
        {
            const short* src = &xt[((long)(b * HW + n0 + tid)) * CC + ks * 32];
            int4 v0 = *(const int4*)src;
            int4 v1 = *(const int4*)(src + 8);
            int4 v2 = *(const int4*)(src + 16);
            int4 v3 = *(const int4*)(src + 24);
            short* dst = &x_lds[tid * 40];
            *(int4*)dst = v0; *(int4*)(dst + 8) = v1;
            *(int4*)(dst + 16) = v2; *(int4*)(dst + 24) = v3;
        }
        __syncthreads();

        bf16x8 a[4], bf[6];
        #pragma unroll
        for (int nf = 0; nf < 4; ++nf)
            a[nf] = *(const bf16x8*)&x_lds[(wvid * 64 + nf * 16 + l15) * 40 + 8 * g];
        #pragma unroll
        for (int of = 0; of < 6; ++of)
            bf[of] = *(const bf16x8*)&w_lds[(of * 16 + l15) * 264 + ks * 32 + 8 * g];
        #pragma unroll
        for (int nf = 0; nf < 4; ++nf)
            #pragma unroll
            for (int of = 0; of < 6; ++of)
                acc[nf][of] = __builtin_amdgcn_mfma_f32_16x16x32_bf16(a[nf], bf[of], acc[nf][of], 0, 0, 0);
    }

    // write y_pm[n][o]
    #pragma unroll
    for (int nf = 0; nf < 4; ++nf) {
        #pragma unroll
        for (int of = 0; of < 6; ++of) {
            int o = o0 + of * 16 + l15;
            long nb = (long)(b * HW + n0 + wvid * 64 + nf * 16 + 4 * g);
            #pragma unroll
            for (int r = 0; r < 4; ++r)
                y[(nb + r) * 192 + o] = f2b(acc[nf][of][r]);
        }
    }
}

// ---------------------------------------------------------------------------
// Kernel 2: 2x2 maxpool from y_pm. kT[b][m][32] direct; vp[b][c][m] via
// LDS transpose (pitch 136).
// ---------------------------------------------------------------------------
__global__ __launch_bounds__(256) void k_pool(
    const short* __restrict__ y, short* __restrict__ kT, short* __restrict__ vp)
{
    __shared__ short t[64 * 136];
    const int bid = blockIdx.x;
    const int mt = bid & 15;
    const int b  = bid >> 4;
    const int m0 = mt * 64;
    const int tid = threadIdx.x;

    // k-branch: one (m, 8c) chunk per thread
    {
        int ml = tid >> 2, ci = (tid & 3) * 8;
        int pp = m0 + ml;
        int ph = pp >> 5, pw = pp & 31;
        const short* src = &y[((long)(b * HW) + ph * 128 + pw * 2) * 192 + 32 + ci];
        int4 s0 = *(const int4*)src;
        int4 s1 = *(const int4*)(src + 192);
        int4 s2 = *(const int4*)(src + 12288);
        int4 s3 = *(const int4*)(src + 12480);
        const short *a = (const short*)&s0, *bb = (const short*)&s1,
                    *c = (const short*)&s2, *d = (const short*)&s3;
        short o8[8];
        #pragma unroll
        for (int j = 0; j < 8; ++j)
            o8[j] = f2b(fmaxf(fmaxf(b2f(a[j]), b2f(bb[j])), fmaxf(b2f(c[j]), b2f(d[j]))));
        *(int4*)&kT[((long)(b * MP + pp)) * CQ + ci] = *(int4*)o8;
    }
    // v-branch: pool into LDS tile [64 m][128 c]
    #pragma unroll
    for (int jj = 0; jj < 4; ++jj) {
        int idx = tid + jj * 256;
        int ml = idx >> 4, ci = (idx & 15) * 8;
        int pp = m0 + ml;
        int ph = pp >> 5, pw = pp & 31;
        const short* src = &y[((long)(b * HW) + ph * 128 + pw * 2) * 192 + 64 + ci];
        int4 s0 = *(const int4*)src;
        int4 s1 = *(const int4*)(src + 192);
        int4 s2 = *(const int4*)(src + 12288);
        int4 s3 = *(const int4*)(src + 12480);
        const short *a = (const short*)&s0, *bb = (const short*)&s1,
                    *c = (const short*)&s2, *d = (const short*)&s3;
        short o8[8];
        #pragma unroll
        for (int j = 0; j < 8; ++j)
            o8[j] = f2b(fmaxf(fmaxf(b2f(a[j]), b2f(bb[j])), fmaxf(b2f(c[j]), b2f(d[j]))));
        *(int4*)&t[ml * 136 + ci] = *(int4*)o8;
    }
    __syncthreads();
    // transpose out: vp[c][m0..m0+63]
    {
        int c = tid & 127, mc = (tid >> 7) * 32;
        short buf[32];
        #pragma unroll
        for (int mm = 0; mm < 32; ++mm) buf[mm] = t[(mc + mm) * 136 + c];
        short* dst = &vp[((long)(b * CV + c)) * MP + m0 + mc];
        *(int4*)dst = *(int4*)&buf[0];
        *(int4*)(dst + 8)  = *(int4*)&buf[8];
        *(int4*)(dst + 16) = *(int4*)&buf[16];
        *(int4*)(dst + 24) = *(int4*)&buf[24];
    }
}

// ---------------------------------------------------------------------------
// Kernel 3: MFMA flash attention (swapped-operand). Block = 128 thr (2 waves),
// wave = 32 queries. QK^T: D[m][q] -> per-lane online softmax over q=l15.
// PV: mfma(P as A, V^T as B) -> D[row=q][col=c] -> ctx position-major bf16.
// Per-row alpha/inv fetched via __shfl (softmax state lives at q=l15).
// ---------------------------------------------------------------------------
__global__ __launch_bounds__(128) void k_attn(
    const short* __restrict__ y,      // y_pm: q = cols 0..31
    const short* __restrict__ kT,     // [b][1024][32]
    const short* __restrict__ vp,     // [b][128][1024]
    short* __restrict__ ctx)          // [b][4096][128] bf16
{
    __shared__ short p_lds[2][2][16][40];
    const int tid  = threadIdx.x;
    const int lane = tid & 63;
    const int wid  = tid >> 6;
    const int b    = blockIdx.x >> 6;
    const int q0   = (blockIdx.x & 63) * 64 + wid * 32;
    const int l15  = lane & 15;
    const int g    = lane >> 4;

    // Q B-frags: direct contiguous loads from position-major y
    bf16x8 qf[2];
    const short* yq = y + (long)b * HW * 192;
    #pragma unroll
    for (int si = 0; si < 2; ++si)
        qf[si] = *(const bf16x8*)&yq[(long)(q0 + si * 16 + l15) * 192 + 8 * g];

    float m_run[2] = {-INFINITY, -INFINITY};
    float l_run[2] = {0.f, 0.f};
    f32x4 acc[2][8];
    #pragma unroll
    for (int si = 0; si < 2; ++si)
        #pragma unroll
        for (int ct = 0; ct < 8; ++ct)
            acc[si][ct] = (f32x4){0.f, 0.f, 0.f, 0.f};

    const short* kTb = kT + (long)b * MP * CQ;
    const short* vpb = vp + (long)b * CV * MP;

    for (int mt = 0; mt < 32; ++mt) {
        const int m0 = mt * 32;
        bf16x8 ka0 = *(const bf16x8*)&kTb[(m0 + l15) * CQ + 8 * g];
        bf16x8 ka1 = *(const bf16x8*)&kTb[(m0 + 16 + l15) * CQ + 8 * g];
        bf16x8 va[8];
        #pragma unroll
        for (int ct = 0; ct < 8; ++ct)
            va[ct] = *(const bf16x8*)&vpb[(ct * 16 + l15) * MP + m0 + 8 * g];

        #pragma unroll
        for (int si = 0; si < 2; ++si) {
            f32x4 s0 = (f32x4){0.f, 0.f, 0.f, 0.f};
            f32x4 s1 = (f32x4){0.f, 0.f, 0.f, 0.f};
            s0 = __builtin_amdgcn_mfma_f32_16x16x32_bf16(ka0, qf[si], s0, 0, 0, 0);
            s1 = __builtin_amdgcn_mfma_f32_16x16x32_bf16(ka1, qf[si], s1, 0, 0, 0);
            float tmax = fmaxf(fmaxf(fmaxf(s0[0], s0[1]), fmaxf(s0[2], s0[3])),
                               fmaxf(fmaxf(s1[0], s1[1]), fmaxf(s1[2], s1[3])));
            tmax = fmaxf(tmax, __shfl_xor(tmax, 16, 64));
            tmax = fmaxf(tmax, __shfl_xor(tmax, 32, 64));
            float mr = m_run[si];
            if (!__all(tmax <= mr + 8.0f)) {      // defer-rescale (T13)
                float nm = fmaxf(mr, tmax);
                float alpha = __expf(mr - nm);
                l_run[si] *= alpha;
                #pragma unroll
                for (int r = 0; r < 4; ++r) {
                    float ar = __shfl(alpha, 4 * g + r, 64);   // alpha for row q=4g+r
                    #pragma unroll
                    for (int ct = 0; ct < 8; ++ct) acc[si][ct][r] *= ar;
                }
                m_run[si] = nm;
                mr = nm;
            }
            float p[8];
            #pragma unroll
            for (int r = 0; r < 4; ++r) { p[r] = __expf(s0[r] - mr); p[4 + r] = __expf(s1[r] - mr); }
            float ts = ((p[0] + p[1]) + (p[2] + p[3])) + ((p[4] + p[5]) + (p[6] + p[7]));
            ts += __shfl_xor(ts, 16, 64);
            ts += __shfl_xor(ts, 32, 64);
            l_run[si] += ts;
            short4v w0 = { f2b(p[0]), f2b(p[1]), f2b(p[2]), f2b(p[3]) };
            short4v w1 = { f2b(p[4]), f2b(p[5]), f2b(p[6]), f2b(p[7]) };
            *(short4v*)&p_lds[wid][si][l15][4 * g]      = w0;
            *(short4v*)&p_lds[wid][si][l15][16 + 4 * g] = w1;
        }
        #pragma unroll
        for (int si = 0; si < 2; ++si) {
            bf16x8 pf = *(const bf16x8*)&p_lds[wid][si][l15][8 * g];  // A[q][m]
            #pragma unroll
            for (int ct = 0; ct < 8; ++ct)
                acc[si][ct] = __builtin_amdgcn_mfma_f32_16x16x32_bf16(pf, va[ct], acc[si][ct], 0, 0, 0);
        }
    }

    #pragma unroll
    for (int si = 0; si < 2; ++si) {
        float inv = 1.f / l_run[si];
        #pragma unroll
        for (int r = 0; r < 4; ++r) {
            float invr = __shfl(inv, 4 * g + r, 64);
            long q = q0 + si * 16 + 4 * g + r;
            short* cb = &ctx[((long)b * HW + q) * CV];
            #pragma unroll
            for (int ct = 0; ct < 8; ++ct)
                cb[ct * 16 + l15] = f2b(acc[si][ct][r] * invr);
        }
    }
}

// ---------------------------------------------------------------------------
// Kernel 4: out = gamma * wo @ ctx + x as bf16 MFMA. D[row=o][col=n],
// A = wo rows (LDS), B = ctx_pm rows (LDS). Coalesced fp32 out + residual.
// Block: 256 thr, tile o=128 x n=256, K=128. LDS 102 KB -> 1 block/CU.
// ---------------------------------------------------------------------------
__global__ __launch_bounds__(256) void k_out(
    const short* __restrict__ ctx, const float* __restrict__ wo,
    const float* __restrict__ x, const float* __restrict__ gamma,
    float* __restrict__ out)
{
    __shared__ short c_lds[256 * 136];
    __shared__ short w_lds[128 * 136];
    const int bid = blockIdx.x;
    const int oc = bid & 1;
    const int nt = (bid >> 1) & 15;
    const int b  = bid >> 5;
    const int o0 = oc * 128, n0 = nt * 256;
    const int tid = threadIdx.x;
    const int lane = tid & 63;
    const int l15 = lane & 15, g = lane >> 4;

    // stage ctx tile: row per thread
    {
        const short* src = &ctx[((long)(b * HW + n0 + tid)) * CV];
        short* dst = &c_lds[tid * 136];
        #pragma unroll
        for (int j = 0; j < 16; ++j)
            *(int4*)(dst + 8 * j) = *(const int4*)(src + 8 * j);
    }
    // stage wo (f32 -> bf16)
    for (int it = 0; it < 16; ++it) {
        int idx = tid + it * 256;            // quad over 128*32
        int ol = idx >> 5, cq = (idx & 31) * 4;
        float4 w = *(const float4*)&wo[(o0 + ol) * CV + cq];
        short4v p = { f2b(w.x), f2b(w.y), f2b(w.z), f2b(w.w) };
        *(short4v*)&w_lds[ol * 136 + cq] = p;
    }
    __syncthreads();

    const int wvid = tid >> 6;
    const int ow = (wvid & 1) * 64, nw = (wvid >> 1) * 128;
    f32x4 acc[4][8];
    #pragma unroll
    for (int of = 0; of < 4; ++of)
        #pragma unroll
        for (int nf = 0; nf < 8; ++nf) acc[of][nf] = (f32x4){0.f, 0.f, 0.f, 0.f};

    #pragma unroll
    for (int ks = 0; ks < 4; ++ks) {
        bf16x8 af[4], bf[8];
        #pragma unroll
        for (int of = 0; of < 4; ++of)
            af[of] = *(const bf16x8*)&w_lds[(ow + of * 16 + l15) * 136 + ks * 32 + 8 * g];
        #pragma unroll
        for (int nf = 0; nf < 8; ++nf)
            bf[nf] = *(const bf16x8*)&c_lds[(nw + nf * 16 + l15) * 136 + ks * 32 + 8 * g];
        #pragma unroll
        for (int of = 0; of < 4; ++of)
            #pragma unroll
            for (int nf = 0; nf < 8; ++nf)
                acc[of][nf] = __builtin_amdgcn_mfma_f32_16x16x32_bf16(af[of], bf[nf], acc[of][nf], 0, 0, 0);
    }

    const float gma = gamma[0];
    #pragma unroll
    for (int of = 0; of < 4; ++of) {
        #pragma unroll
        for (int r = 0; r < 4; ++r) {
            int o = o0 + ow + of * 16 + 4 * g + r;
            #pragma unroll
            for (int nf = 0; nf < 8; ++nf) {
                int n = n0 + nw + nf * 16 + l15;
                long idx = (long)(b * CC + o) * HW + n;
                out[idx] = gma * acc[of][nf][r] + x[idx];
            }
        }
    }
}

// ---------------------------------------------------------------------------
extern "C" void kernel_launch(void* const* d_in, const int* in_sizes, int n_in,
                              void* d_out, int out_size, void* d_ws, size_t ws_size,
                              hipStream_t stream) {
    const float* x     = (const float*)d_in[0];
    const float* wq    = (const float*)d_in[1];
    const float* wk    = (const float*)d_in[2];
    const float* wv    = (const float*)d_in[3];
    const float* wo    = (const float*)d_in[4];
    const float* gamma = (const float*)d_in[5];
    float* out = (float*)d_out;
    float* ws  = (float*)d_ws;

    short* xt  = (short*)(ws + XT_OFF);
    short* y   = (short*)(ws + Y_OFF);
    short* kT  = (short*)(ws + KT_OFF);
    short* vp  = (short*)(ws + VP_OFF);
    short* ctx = (short*)(ws + CT_OFF);

    k_xt  <<<dim3(2048), dim3(256), 0, stream>>>(x, xt);
    k_qkv <<<dim3(256),  dim3(256), 0, stream>>>(wq, wk, wv, xt, y);
    k_pool<<<dim3(128),  dim3(256), 0, stream>>>(y, kT, vp);
    k_attn<<<dim3(512),  dim3(128), 0, stream>>>(y, kT, vp, ctx);
    k_out <<<dim3(256),  dim3(256), 0, stream>>>(ctx, wo, x, gamma, out);
}